// Round 1
// baseline (18897.864 us; speedup 1.0000x reference)
//
#include <hip/hip_runtime.h>
#include <math.h>

#define H    256
#define G4H  1024
#define CIN  512
#define BB   16
#define TT   2048
#define CHUNK 256
#define NPH  8   // TT/CHUNK

// ---- workspace layout (in floats) ----
#define OFF_WPACK   ((size_t)0)                       // 2*256*256*4 = 524288
#define OFF_PROJF   ((size_t)524288)                  // 256*16*1024 = 4194304
#define OFF_PROJB   (OFF_PROJF + (size_t)4194304)
#define OFF_HBUF    (OFF_PROJB + (size_t)4194304)     // 2048*16*512 = 16777216
#define OFF_STATS   (OFF_HBUF  + (size_t)16777216)    // 1024
#define OFF_HSTATE  (OFF_STATS + (size_t)1024)        // 32*256
#define OFF_CSTATE  (OFF_HSTATE + (size_t)8192)       // 32*256
#define OFF_W2      (OFF_CSTATE + (size_t)8192)       // 1024
#define OFF_B2      (OFF_W2 + (size_t)1024)           // 16
#define OFF_SAMP    (OFF_B2 + (size_t)16)             // 16*2048

// ---------------- K0: pack Whh as float4(i,f,g,o) per (dir,k,j); zero state/stats ----------------
__global__ __launch_bounds__(256) void k0_init(
    const float* __restrict__ WhhF, const float* __restrict__ WhhB,
    float4* __restrict__ wpack, float* __restrict__ stats,
    float* __restrict__ hstate, float* __restrict__ cstate) {
  int idx = blockIdx.x * 256 + threadIdx.x;
  if (idx < 2 * 256 * 256) {
    int dir = idx >> 16, k = (idx >> 8) & 255, j = idx & 255;
    const float* W = dir ? WhhB : WhhF;
    wpack[idx] = make_float4(W[(size_t)j * H + k], W[(size_t)(H + j) * H + k],
                             W[(size_t)(2 * H + j) * H + k], W[(size_t)(3 * H + j) * H + k]);
  }
  if (idx < 1024) stats[idx] = 0.f;
  if (idx < 32 * H) { hstate[idx] = 0.f; cstate[idx] = 0.f; }
}

// ---------------- K1: proj[tc][b][g] = sum_c x[b][c][t] * Wih[g][c] + bih[g]+bhh[g] ----------------
__global__ __launch_bounds__(256) void k1_proj(
    const float* __restrict__ x, const float* __restrict__ Wih,
    const float* __restrict__ bih, const float* __restrict__ bhh,
    float* __restrict__ proj, int t0) {
  __shared__ float Xs[16][65];   // [c][t]
  __shared__ float Ws[16][68];   // [c][g]
  int tid = threadIdx.x;
  int tbase = t0 + blockIdx.x * 64;
  int gbase = blockIdx.y * 64;
  int b = blockIdx.z;
  int tx = tid & 15, ty = tid >> 4;
  float acc[4][4];
#pragma unroll
  for (int i = 0; i < 4; i++)
#pragma unroll
    for (int j = 0; j < 4; j++) acc[i][j] = 0.f;

  int lt = tid & 63, lk = tid >> 6;  // Xs loader
  int wk = tid & 15, wg = tid >> 4;  // Ws loader
  const float* xb = x + (size_t)b * CIN * TT;

  for (int c0 = 0; c0 < CIN; c0 += 16) {
    __syncthreads();
#pragma unroll
    for (int q = 0; q < 4; q++)
      Xs[lk + 4 * q][lt] = xb[(size_t)(c0 + lk + 4 * q) * TT + tbase + lt];
#pragma unroll
    for (int q = 0; q < 4; q++)
      Ws[wk][wg + 16 * q] = Wih[(size_t)(gbase + wg + 16 * q) * CIN + c0 + wk];
    __syncthreads();
#pragma unroll
    for (int kk = 0; kk < 16; kk++) {
      float a0 = Xs[kk][tx * 4 + 0], a1 = Xs[kk][tx * 4 + 1];
      float a2 = Xs[kk][tx * 4 + 2], a3 = Xs[kk][tx * 4 + 3];
      float b0 = Ws[kk][ty * 4 + 0], b1 = Ws[kk][ty * 4 + 1];
      float b2 = Ws[kk][ty * 4 + 2], b3 = Ws[kk][ty * 4 + 3];
      acc[0][0] += a0 * b0; acc[0][1] += a0 * b1; acc[0][2] += a0 * b2; acc[0][3] += a0 * b3;
      acc[1][0] += a1 * b0; acc[1][1] += a1 * b1; acc[1][2] += a1 * b2; acc[1][3] += a1 * b3;
      acc[2][0] += a2 * b0; acc[2][1] += a2 * b1; acc[2][2] += a2 * b2; acc[2][3] += a2 * b3;
      acc[3][0] += a3 * b0; acc[3][1] += a3 * b1; acc[3][2] += a3 * b2; acc[3][3] += a3 * b3;
    }
  }
  int g0 = gbase + ty * 4;
  float bias0 = bih[g0 + 0] + bhh[g0 + 0];
  float bias1 = bih[g0 + 1] + bhh[g0 + 1];
  float bias2 = bih[g0 + 2] + bhh[g0 + 2];
  float bias3 = bih[g0 + 3] + bhh[g0 + 3];
#pragma unroll
  for (int i = 0; i < 4; i++) {
    int tc = blockIdx.x * 64 + tx * 4 + i;  // index within chunk
    float4 st = make_float4(acc[i][0] + bias0, acc[i][1] + bias1,
                            acc[i][2] + bias2, acc[i][3] + bias3);
    *(float4*)(proj + ((size_t)tc * BB + b) * G4H + g0) = st;
  }
}

// ---------------- K2: LSTM recurrence, one WG per (dir,b) ----------------
__global__ __launch_bounds__(256) void k2_rec(
    const float4* __restrict__ wpack, const float* __restrict__ projF,
    const float* __restrict__ projB, float* __restrict__ hbuf,
    float* __restrict__ hstate, float* __restrict__ cstate,
    float* __restrict__ stats, int t0f, int t0b, int first) {
  __shared__ float h_lds[H];
  int wg = blockIdx.x;
  int dir = wg >> 4, b = wg & 15;
  int j = threadIdx.x;
  size_t sidx = (size_t)wg * H + j;
  float h, c;
  if (first) { h = 0.f; c = 0.f; }
  else       { h = hstate[sidx]; c = cstate[sidx]; }
  h_lds[j] = h;
  const float4* wp = wpack + (size_t)dir * 65536 + j;
  const float* pbase = dir ? projB : projF;
  float s1 = 0.f, s2 = 0.f;

  for (int step = 0; step < CHUNK; ++step) {
    int tc = dir ? (CHUNK - 1 - step) : step;
    int t  = (dir ? t0b : t0f) + tc;
    const float* p = pbase + ((size_t)tc * BB + b) * G4H + j;
    float4 acc = make_float4(p[0], p[H], p[2 * H], p[3 * H]);
    __syncthreads();  // h_lds ready
#pragma unroll 16
    for (int k = 0; k < H; ++k) {
      float hk = h_lds[k];
      float4 w = wp[(size_t)k * H];
      acc.x += w.x * hk; acc.y += w.y * hk; acc.z += w.z * hk; acc.w += w.w * hk;
    }
    float ig = 1.f / (1.f + expf(-acc.x));
    float fg = 1.f / (1.f + expf(-acc.y));
    float gg = tanhf(acc.z);
    float og = 1.f / (1.f + expf(-acc.w));
    c = fg * c + ig * gg;
    h = og * tanhf(c);
    s1 += h; s2 += h * h;
    hbuf[((size_t)t * BB + b) * 512 + dir * H + j] = h;
    __syncthreads();  // all reads of old h done
    h_lds[j] = h;
  }
  hstate[sidx] = h; cstate[sidx] = c;
  atomicAdd(&stats[dir * H + j], s1);
  atomicAdd(&stats[512 + dir * H + j], s2);
}

// ---------------- K3: fold BN into linear ----------------
__global__ __launch_bounds__(512) void k3_prep(
    const float* __restrict__ stats, const float* __restrict__ gamma,
    const float* __restrict__ beta, const float* __restrict__ Wlin,
    const float* __restrict__ blin, float* __restrict__ w2, float* __restrict__ b2) {
  __shared__ float r0[512], r1[512];
  int ch = threadIdx.x;
  float mean = stats[ch] * (1.f / 32768.f);
  float var  = stats[512 + ch] * (1.f / 32768.f) - mean * mean;
  float s = gamma[ch] * rsqrtf(var + 1e-5f);
  float w0 = Wlin[ch], w1 = Wlin[512 + ch];
  w2[ch] = w0 * s; w2[512 + ch] = w1 * s;
  float tt = beta[ch] - mean * s;
  r0[ch] = w0 * tt; r1[ch] = w1 * tt;
  __syncthreads();
  for (int off = 256; off > 0; off >>= 1) {
    if (ch < off) { r0[ch] += r0[ch + off]; r1[ch] += r1[ch + off]; }
    __syncthreads();
  }
  if (ch == 0) { b2[0] = blin[0] + r0[0]; b2[1] = blin[1] + r1[0]; }
}

// ---------------- K4: posterior + gumbel hard sample; one wave per (b,t) ----------------
__global__ __launch_bounds__(256) void k4_post(
    const float* __restrict__ hbuf, const float* __restrict__ w2,
    const float* __restrict__ b2, const float* __restrict__ u,
    const float* __restrict__ e, float* __restrict__ post,
    float* __restrict__ samp) {
  int wid = (blockIdx.x * 256 + threadIdx.x) >> 6;
  int lane = threadIdx.x & 63;
  int b = wid >> 11, t = wid & 2047;
  const float* hr = hbuf + ((size_t)t * BB + b) * 512;
  int c0 = lane * 8;
  float d0 = 0.f, d1 = 0.f;
#pragma unroll
  for (int q = 0; q < 8; q++) {
    float hv = hr[c0 + q];
    d0 += w2[c0 + q] * hv;
    d1 += w2[512 + c0 + q] * hv;
  }
#pragma unroll
  for (int off = 32; off > 0; off >>= 1) {
    d0 += __shfl_xor(d0, off, 64);
    d1 += __shfl_xor(d1, off, 64);
  }
  if (lane == 0) {
    float z0 = (d0 + b2[0]) * 0.1f, z1 = (d1 + b2[1]) * 0.1f;
    float m = fmaxf(z0, z1);
    float e0 = expf(z0 - m), e1 = expf(z1 - m);
    float inv = 1.f / (e0 + e1);
    float p0 = e0 * inv, p1 = e1 * inv;
    size_t o = (size_t)b * TT + t;
    post[o * 2] = p0; post[o * 2 + 1] = p1;
    float u0 = u[o * 2], u1 = u[o * 2 + 1];
    float g0 = -logf(-logf(u0 + 1e-20f) + 1e-20f);
    float g1 = -logf(-logf(u1 + 1e-20f) + 1e-20f);
    float a0 = logf(p0) + g0, a1 = logf(p1) + g1;
    samp[o] = (a1 > a0) ? e[o] : 0.f;  // strict >: np.argmax tie -> class 0
  }
}

// ---------------- K5: 3x median-of-5 (reflect pad), one WG per b ----------------
#define MSWAP(a, b) { float lo_ = fminf(a, b); b = fmaxf(a, b); a = lo_; }
__global__ __launch_bounds__(256) void k5_median(
    const float* __restrict__ samp, float* __restrict__ mask) {
  __shared__ float buf[2][TT];
  int b = blockIdx.x, tid = threadIdx.x;
  for (int i = tid; i < TT; i += 256) buf[0][i] = samp[(size_t)b * TT + i];
  __syncthreads();
  int src = 0;
  for (int pass = 0; pass < 3; ++pass) {
    for (int i = tid; i < TT; i += 256) {
      float v0, v1, v2, v3, v4;
      {
        int i0 = i - 2; i0 = i0 < 0 ? -i0 : i0;
        int i1 = i - 1; i1 = i1 < 0 ? -i1 : i1;
        int i3 = i + 1; i3 = i3 > TT - 1 ? 2 * (TT - 1) - i3 : i3;
        int i4 = i + 2; i4 = i4 > TT - 1 ? 2 * (TT - 1) - i4 : i4;
        v0 = buf[src][i0]; v1 = buf[src][i1]; v2 = buf[src][i];
        v3 = buf[src][i3]; v4 = buf[src][i4];
      }
      MSWAP(v0, v1); MSWAP(v3, v4); MSWAP(v2, v4); MSWAP(v2, v3);
      MSWAP(v1, v4); MSWAP(v0, v3); MSWAP(v0, v2); MSWAP(v1, v3);
      MSWAP(v1, v2);
      buf[1 - src][i] = v2;
    }
    __syncthreads();
    src = 1 - src;
  }
  for (int i = tid; i < TT; i += 256) mask[(size_t)b * TT + i] = buf[src][i];
}

extern "C" void kernel_launch(void* const* d_in, const int* in_sizes, int n_in,
                              void* d_out, int out_size, void* d_ws, size_t ws_size,
                              hipStream_t stream) {
  const float* x    = (const float*)d_in[0];
  const float* e    = (const float*)d_in[1];
  const float* u    = (const float*)d_in[2];
  const float* WihF = (const float*)d_in[3];
  const float* WhhF = (const float*)d_in[4];
  const float* bihF = (const float*)d_in[5];
  const float* bhhF = (const float*)d_in[6];
  const float* WihB = (const float*)d_in[7];
  const float* WhhB = (const float*)d_in[8];
  const float* bihB = (const float*)d_in[9];
  const float* bhhB = (const float*)d_in[10];
  const float* gamma= (const float*)d_in[11];
  const float* beta = (const float*)d_in[12];
  const float* Wlin = (const float*)d_in[13];
  const float* blin = (const float*)d_in[14];

  float* ws = (float*)d_ws;
  float4* wpack = (float4*)(ws + OFF_WPACK);
  float* projF  = ws + OFF_PROJF;
  float* projB  = ws + OFF_PROJB;
  float* hbuf   = ws + OFF_HBUF;
  float* stats  = ws + OFF_STATS;
  float* hstate = ws + OFF_HSTATE;
  float* cstate = ws + OFF_CSTATE;
  float* w2     = ws + OFF_W2;
  float* b2     = ws + OFF_B2;
  float* samp   = ws + OFF_SAMP;

  float* post = (float*)d_out;
  float* mask = (float*)d_out + (size_t)BB * TT * 2;

  hipLaunchKernelGGL(k0_init, dim3(512), dim3(256), 0, stream,
                     WhhF, WhhB, wpack, stats, hstate, cstate);
  for (int p = 0; p < NPH; ++p) {
    int t0f = p * CHUNK;
    int t0b = (NPH - 1 - p) * CHUNK;
    hipLaunchKernelGGL(k1_proj, dim3(4, 16, 16), dim3(256), 0, stream,
                       x, WihF, bihF, bhhF, projF, t0f);
    hipLaunchKernelGGL(k1_proj, dim3(4, 16, 16), dim3(256), 0, stream,
                       x, WihB, bihB, bhhB, projB, t0b);
    hipLaunchKernelGGL(k2_rec, dim3(32), dim3(256), 0, stream,
                       wpack, projF, projB, hbuf, hstate, cstate, stats,
                       t0f, t0b, p == 0 ? 1 : 0);
  }
  hipLaunchKernelGGL(k3_prep, dim3(1), dim3(512), 0, stream,
                     stats, gamma, beta, Wlin, blin, w2, b2);
  hipLaunchKernelGGL(k4_post, dim3(8192), dim3(256), 0, stream,
                     hbuf, w2, b2, u, e, post, samp);
  hipLaunchKernelGGL(k5_median, dim3(16), dim3(256), 0, stream, samp, mask);
}

// Round 2
// 18213.408 us; speedup vs baseline: 1.0376x; 1.0376x over previous
//
#include <hip/hip_runtime.h>
#include <math.h>

#define H    256
#define G4H  1024
#define CIN  512
#define BB   16
#define TT   2048
#define CHUNK 256
#define NPH  8   // TT/CHUNK

// ---- workspace layout (in floats) ----
#define OFF_WQ      ((size_t)0)                        // 2*64*1024 float4 = 524288 floats
#define OFF_PROJF   ((size_t)524288)                   // 256*16*1024 = 4194304
#define OFF_PROJB   (OFF_PROJF + (size_t)4194304)
#define OFF_HBUF    (OFF_PROJB + (size_t)4194304)      // 2048*16*512 = 16777216
#define OFF_STATS   (OFF_HBUF  + (size_t)16777216)     // 1024
#define OFF_HSTATE  (OFF_STATS + (size_t)1024)         // 32*256
#define OFF_CSTATE  (OFF_HSTATE + (size_t)8192)        // 32*4*64
#define OFF_HX      (OFF_CSTATE + (size_t)8192)        // 32*2*256
#define OFF_FLAGS   (OFF_HX + (size_t)16384)           // NPH*32 ints
#define OFF_W2      (OFF_FLAGS + (size_t)256)          // 1024
#define OFF_B2      (OFF_W2 + (size_t)1024)            // 16
#define OFF_SAMP    (OFF_B2 + (size_t)16)              // 16*2048

// ---------------- K0: repack Whh as wq[dir][q][row] float4 (row k-chunk q); zero stats+flags ----------------
__global__ __launch_bounds__(256) void k0_init(
    const float* __restrict__ WhhF, const float* __restrict__ WhhB,
    float4* __restrict__ wq, float* __restrict__ stats, int* __restrict__ flags) {
  int idx = blockIdx.x * 256 + threadIdx.x;
  if (idx < 2 * 64 * 1024) {
    int dir = idx >> 16, rem = idx & 65535;
    int q = rem >> 10, row = rem & 1023;
    const float* W = (dir ? WhhB : WhhF) + (size_t)row * H + 4 * q;
    wq[idx] = make_float4(W[0], W[1], W[2], W[3]);
  }
  if (idx < 1024) stats[idx] = 0.f;
  if (idx < NPH * 32) flags[idx] = 0;
}

// ---------------- K1: proj[tc][b][g] = sum_c x[b][c][t] * Wih[g][c] + bih[g]+bhh[g] (both dirs) ----------------
__global__ __launch_bounds__(256) void k1_proj(
    const float* __restrict__ x,
    const float* __restrict__ WihF, const float* __restrict__ bihF, const float* __restrict__ bhhF,
    const float* __restrict__ WihB, const float* __restrict__ bihB, const float* __restrict__ bhhB,
    float* __restrict__ projF, float* __restrict__ projB, int t0f, int t0b) {
  __shared__ float Xs[16][65];   // [c][t]
  __shared__ float Ws[16][68];   // [c][g]
  int tid = threadIdx.x;
  int b = blockIdx.z & 15, dir = blockIdx.z >> 4;
  const float* Wih = dir ? WihB : WihF;
  const float* bih = dir ? bihB : bihF;
  const float* bhh = dir ? bhhB : bhhF;
  float* proj = dir ? projB : projF;
  int tbase = (dir ? t0b : t0f) + blockIdx.x * 64;
  int gbase = blockIdx.y * 64;
  int tx = tid & 15, ty = tid >> 4;
  float acc[4][4];
#pragma unroll
  for (int i = 0; i < 4; i++)
#pragma unroll
    for (int j = 0; j < 4; j++) acc[i][j] = 0.f;

  int lt = tid & 63, lk = tid >> 6;  // Xs loader
  int wk = tid & 15, wg = tid >> 4;  // Ws loader
  const float* xb = x + (size_t)b * CIN * TT;

  for (int c0 = 0; c0 < CIN; c0 += 16) {
    __syncthreads();
#pragma unroll
    for (int q = 0; q < 4; q++)
      Xs[lk + 4 * q][lt] = xb[(size_t)(c0 + lk + 4 * q) * TT + tbase + lt];
#pragma unroll
    for (int q = 0; q < 4; q++)
      Ws[wk][wg + 16 * q] = Wih[(size_t)(gbase + wg + 16 * q) * CIN + c0 + wk];
    __syncthreads();
#pragma unroll
    for (int kk = 0; kk < 16; kk++) {
      float a0 = Xs[kk][tx * 4 + 0], a1 = Xs[kk][tx * 4 + 1];
      float a2 = Xs[kk][tx * 4 + 2], a3 = Xs[kk][tx * 4 + 3];
      float b0 = Ws[kk][ty * 4 + 0], b1 = Ws[kk][ty * 4 + 1];
      float b2 = Ws[kk][ty * 4 + 2], b3 = Ws[kk][ty * 4 + 3];
      acc[0][0] += a0 * b0; acc[0][1] += a0 * b1; acc[0][2] += a0 * b2; acc[0][3] += a0 * b3;
      acc[1][0] += a1 * b0; acc[1][1] += a1 * b1; acc[1][2] += a1 * b2; acc[1][3] += a1 * b3;
      acc[2][0] += a2 * b0; acc[2][1] += a2 * b1; acc[2][2] += a2 * b2; acc[2][3] += a2 * b3;
      acc[3][0] += a3 * b0; acc[3][1] += a3 * b1; acc[3][2] += a3 * b2; acc[3][3] += a3 * b3;
    }
  }
  int g0 = gbase + ty * 4;
  float bias0 = bih[g0 + 0] + bhh[g0 + 0];
  float bias1 = bih[g0 + 1] + bhh[g0 + 1];
  float bias2 = bih[g0 + 2] + bhh[g0 + 2];
  float bias3 = bih[g0 + 3] + bhh[g0 + 3];
#pragma unroll
  for (int i = 0; i < 4; i++) {
    int tc = blockIdx.x * 64 + tx * 4 + i;  // index within chunk
    float4 st = make_float4(acc[i][0] + bias0, acc[i][1] + bias1,
                            acc[i][2] + bias2, acc[i][3] + bias3);
    *(float4*)(proj + ((size_t)tc * BB + b) * G4H + g0) = st;
  }
}

// ---------------- K2: LSTM recurrence. 4 sibling WGs per (dir,b); Whh register-resident ----------------
// bx swizzle: grp = bx & 31 (so siblings share XCD under bx%8 round-robin), s = bx >> 5.
__global__ __launch_bounds__(256, 1) void k2_rec(
    const float4* __restrict__ wq, const float* __restrict__ projF,
    const float* __restrict__ projB, float* __restrict__ hbuf,
    float* __restrict__ hx, int* __restrict__ flags,
    float* __restrict__ hstate, float* __restrict__ cstate,
    float* __restrict__ stats, int t0f, int t0b, int first) {
  __shared__ __align__(16) float h_lds[256];
  __shared__ float gbuf[4][64];
  const int tid = threadIdx.x;
  const int bx = blockIdx.x;
  const int grp = bx & 31, s = bx >> 5;
  const int dir = grp >> 4, b = grp & 15;
  const int gate = tid >> 6, jj = tid & 63;
  const int row = gate * 256 + s * 64 + jj;

  // weights -> VGPRs (64 float4 = 256 regs/thread); coalesced: lanes hit consecutive rows
  float4 w[64];
  const float4* wbase = wq + (size_t)dir * 65536 + row;
#pragma unroll
  for (int q = 0; q < 64; ++q) w[q] = wbase[(size_t)q * 1024];

  // init h (full 256) and own c (64 per WG, held by wave 0 lanes)
  h_lds[tid] = first ? 0.f : hstate[grp * 256 + tid];
  float c = 0.f, s1 = 0.f, s2 = 0.f;
  if (tid < 64 && !first) c = cstate[(grp * 4 + s) * 64 + tid];
  __syncthreads();

  const float* pbase = dir ? projB : projF;
  float* hx_g = hx + grp * 512;  // two 256-float buffers
  int* flag = flags + grp;

  for (int step = 0; step < CHUNK; ++step) {
    int tc = dir ? (CHUNK - 1 - step) : step;
    int t = (dir ? t0b : t0f) + tc;

    float acc = pbase[((size_t)tc * BB + b) * G4H + row];
    const float4* h4 = (const float4*)h_lds;
#pragma unroll
    for (int q = 0; q < 64; ++q) {
      float4 hv = h4[q];  // ds_read_b128 broadcast (all lanes same address)
      acc += w[q].x * hv.x + w[q].y * hv.y + w[q].z * hv.z + w[q].w * hv.w;
    }
    gbuf[gate][jj] = acc;
    __syncthreads();

    if (tid < 64) {
      float gi = gbuf[0][jj], gf = gbuf[1][jj], gg = gbuf[2][jj], go = gbuf[3][jj];
      float ig = 1.f / (1.f + expf(-gi));
      float fg = 1.f / (1.f + expf(-gf));
      float gz = tanhf(gg);
      float og = 1.f / (1.f + expf(-go));
      c = fg * c + ig * gz;
      float h = og * tanhf(c);
      s1 += h; s2 += h * h;
      hbuf[((size_t)t * BB + b) * 512 + dir * 256 + s * 64 + jj] = h;
      __hip_atomic_store(&hx_g[(step & 1) * 256 + s * 64 + jj], h,
                         __ATOMIC_RELAXED, __HIP_MEMORY_SCOPE_AGENT);
      __threadfence();  // drain hx stores (same wave) before flag
      if (tid == 0)
        __hip_atomic_fetch_add(flag, 1, __ATOMIC_RELEASE, __HIP_MEMORY_SCOPE_AGENT);
    }

    if (tid == 0) {
      int target = 4 * (step + 1);
      while (__hip_atomic_load(flag, __ATOMIC_ACQUIRE, __HIP_MEMORY_SCOPE_AGENT) < target) {}
    }
    __syncthreads();
    h_lds[tid] = __hip_atomic_load(&hx_g[(step & 1) * 256 + tid],
                                   __ATOMIC_RELAXED, __HIP_MEMORY_SCOPE_AGENT);
    __syncthreads();
  }

  hstate[grp * 256 + tid] = h_lds[tid];
  if (tid < 64) {
    cstate[(grp * 4 + s) * 64 + tid] = c;
    atomicAdd(&stats[dir * 256 + s * 64 + tid], s1);
    atomicAdd(&stats[512 + dir * 256 + s * 64 + tid], s2);
  }
}

// ---------------- K3: fold BN into linear ----------------
__global__ __launch_bounds__(512) void k3_prep(
    const float* __restrict__ stats, const float* __restrict__ gamma,
    const float* __restrict__ beta, const float* __restrict__ Wlin,
    const float* __restrict__ blin, float* __restrict__ w2, float* __restrict__ b2) {
  __shared__ float r0[512], r1[512];
  int ch = threadIdx.x;
  float mean = stats[ch] * (1.f / 32768.f);
  float var  = stats[512 + ch] * (1.f / 32768.f) - mean * mean;
  float sc = gamma[ch] * rsqrtf(var + 1e-5f);
  float w0 = Wlin[ch], w1 = Wlin[512 + ch];
  w2[ch] = w0 * sc; w2[512 + ch] = w1 * sc;
  float tt = beta[ch] - mean * sc;
  r0[ch] = w0 * tt; r1[ch] = w1 * tt;
  __syncthreads();
  for (int off = 256; off > 0; off >>= 1) {
    if (ch < off) { r0[ch] += r0[ch + off]; r1[ch] += r1[ch + off]; }
    __syncthreads();
  }
  if (ch == 0) { b2[0] = blin[0] + r0[0]; b2[1] = blin[1] + r1[0]; }
}

// ---------------- K4: posterior + gumbel hard sample; one wave per (b,t) ----------------
__global__ __launch_bounds__(256) void k4_post(
    const float* __restrict__ hbuf, const float* __restrict__ w2,
    const float* __restrict__ b2, const float* __restrict__ u,
    const float* __restrict__ e, float* __restrict__ post,
    float* __restrict__ samp) {
  int wid = (blockIdx.x * 256 + threadIdx.x) >> 6;
  int lane = threadIdx.x & 63;
  int b = wid >> 11, t = wid & 2047;
  const float* hr = hbuf + ((size_t)t * BB + b) * 512;
  int c0 = lane * 8;
  float d0 = 0.f, d1 = 0.f;
#pragma unroll
  for (int q = 0; q < 8; q++) {
    float hv = hr[c0 + q];
    d0 += w2[c0 + q] * hv;
    d1 += w2[512 + c0 + q] * hv;
  }
#pragma unroll
  for (int off = 32; off > 0; off >>= 1) {
    d0 += __shfl_xor(d0, off, 64);
    d1 += __shfl_xor(d1, off, 64);
  }
  if (lane == 0) {
    float z0 = (d0 + b2[0]) * 0.1f, z1 = (d1 + b2[1]) * 0.1f;
    float m = fmaxf(z0, z1);
    float e0 = expf(z0 - m), e1 = expf(z1 - m);
    float inv = 1.f / (e0 + e1);
    float p0 = e0 * inv, p1 = e1 * inv;
    size_t o = (size_t)b * TT + t;
    post[o * 2] = p0; post[o * 2 + 1] = p1;
    float u0 = u[o * 2], u1 = u[o * 2 + 1];
    float g0 = -logf(-logf(u0 + 1e-20f) + 1e-20f);
    float g1 = -logf(-logf(u1 + 1e-20f) + 1e-20f);
    float a0 = logf(p0) + g0, a1 = logf(p1) + g1;
    samp[o] = (a1 > a0) ? e[o] : 0.f;  // strict >: np.argmax tie -> class 0
  }
}

// ---------------- K5: 3x median-of-5 (reflect pad), one WG per b ----------------
#define MSWAP(a, b) { float lo_ = fminf(a, b); b = fmaxf(a, b); a = lo_; }
__global__ __launch_bounds__(256) void k5_median(
    const float* __restrict__ samp, float* __restrict__ mask) {
  __shared__ float buf[2][TT];
  int b = blockIdx.x, tid = threadIdx.x;
  for (int i = tid; i < TT; i += 256) buf[0][i] = samp[(size_t)b * TT + i];
  __syncthreads();
  int src = 0;
  for (int pass = 0; pass < 3; ++pass) {
    for (int i = tid; i < TT; i += 256) {
      float v0, v1, v2, v3, v4;
      {
        int i0 = i - 2; i0 = i0 < 0 ? -i0 : i0;
        int i1 = i - 1; i1 = i1 < 0 ? -i1 : i1;
        int i3 = i + 1; i3 = i3 > TT - 1 ? 2 * (TT - 1) - i3 : i3;
        int i4 = i + 2; i4 = i4 > TT - 1 ? 2 * (TT - 1) - i4 : i4;
        v0 = buf[src][i0]; v1 = buf[src][i1]; v2 = buf[src][i];
        v3 = buf[src][i3]; v4 = buf[src][i4];
      }
      MSWAP(v0, v1); MSWAP(v3, v4); MSWAP(v2, v4); MSWAP(v2, v3);
      MSWAP(v1, v4); MSWAP(v0, v3); MSWAP(v0, v2); MSWAP(v1, v3);
      MSWAP(v1, v2);
      buf[1 - src][i] = v2;
    }
    __syncthreads();
    src = 1 - src;
  }
  for (int i = tid; i < TT; i += 256) mask[(size_t)b * TT + i] = buf[src][i];
}

extern "C" void kernel_launch(void* const* d_in, const int* in_sizes, int n_in,
                              void* d_out, int out_size, void* d_ws, size_t ws_size,
                              hipStream_t stream) {
  const float* x    = (const float*)d_in[0];
  const float* e    = (const float*)d_in[1];
  const float* u    = (const float*)d_in[2];
  const float* WihF = (const float*)d_in[3];
  const float* WhhF = (const float*)d_in[4];
  const float* bihF = (const float*)d_in[5];
  const float* bhhF = (const float*)d_in[6];
  const float* WihB = (const float*)d_in[7];
  const float* WhhB = (const float*)d_in[8];
  const float* bihB = (const float*)d_in[9];
  const float* bhhB = (const float*)d_in[10];
  const float* gamma= (const float*)d_in[11];
  const float* beta = (const float*)d_in[12];
  const float* Wlin = (const float*)d_in[13];
  const float* blin = (const float*)d_in[14];

  float* ws = (float*)d_ws;
  float4* wq   = (float4*)(ws + OFF_WQ);
  float* projF  = ws + OFF_PROJF;
  float* projB  = ws + OFF_PROJB;
  float* hbuf   = ws + OFF_HBUF;
  float* stats  = ws + OFF_STATS;
  float* hstate = ws + OFF_HSTATE;
  float* cstate = ws + OFF_CSTATE;
  float* hx     = ws + OFF_HX;
  int*   flags  = (int*)(ws + OFF_FLAGS);
  float* w2     = ws + OFF_W2;
  float* b2     = ws + OFF_B2;
  float* samp   = ws + OFF_SAMP;

  float* post = (float*)d_out;
  float* mask = (float*)d_out + (size_t)BB * TT * 2;

  hipLaunchKernelGGL(k0_init, dim3(512), dim3(256), 0, stream,
                     WhhF, WhhB, wq, stats, flags);
  for (int p = 0; p < NPH; ++p) {
    int t0f = p * CHUNK;
    int t0b = (NPH - 1 - p) * CHUNK;
    hipLaunchKernelGGL(k1_proj, dim3(4, 16, 32), dim3(256), 0, stream,
                       x, WihF, bihF, bhhF, WihB, bihB, bhhB, projF, projB, t0f, t0b);
    hipLaunchKernelGGL(k2_rec, dim3(128), dim3(256), 0, stream,
                       wq, projF, projB, hbuf, hx, flags + p * 32,
                       hstate, cstate, stats, t0f, t0b, p == 0 ? 1 : 0);
  }
  hipLaunchKernelGGL(k3_prep, dim3(1), dim3(512), 0, stream,
                     stats, gamma, beta, Wlin, blin, w2, b2);
  hipLaunchKernelGGL(k4_post, dim3(8192), dim3(256), 0, stream,
                     hbuf, w2, b2, u, e, post, samp);
  hipLaunchKernelGGL(k5_median, dim3(16), dim3(256), 0, stream, samp, mask);
}

// Round 4
// 12101.352 us; speedup vs baseline: 1.5616x; 1.5051x over previous
//
#include <hip/hip_runtime.h>
#include <math.h>

#define H    256
#define G4H  1024
#define CIN  512
#define BB   16
#define TT   2048
#define CHUNK 256
#define NPH  8   // TT/CHUNK

// ---- workspace layout (in floats) ----
#define OFF_WQ      ((size_t)0)                        // 2*32*2048 float4 = 524288 floats
#define OFF_PROJF   ((size_t)524288)                   // 256*16*1024
#define OFF_PROJB   (OFF_PROJF + (size_t)4194304)
#define OFF_HBUF    (OFF_PROJB + (size_t)4194304)      // 2048*16*512
#define OFF_STATS   (OFF_HBUF  + (size_t)16777216)     // 1024
#define OFF_HSTATE  (OFF_STATS + (size_t)1024)         // 32*256
#define OFF_CSTATE  (OFF_HSTATE + (size_t)8192)        // 32*256
#define OFF_HX      (OFF_CSTATE + (size_t)8192)        // 32*2*256
#define OFF_FLAGS   (OFF_HX + (size_t)16384)           // NPH*32*16 ints = 4096
#define OFF_W2      (OFF_FLAGS + (size_t)4096)         // 1024
#define OFF_B2      (OFF_W2 + (size_t)1024)            // 16
#define OFF_SAMP    (OFF_B2 + (size_t)16)              // 16*2048

#define REP32(X) X(0) X(1) X(2) X(3) X(4) X(5) X(6) X(7) X(8) X(9) X(10) X(11) \
  X(12) X(13) X(14) X(15) X(16) X(17) X(18) X(19) X(20) X(21) X(22) X(23) \
  X(24) X(25) X(26) X(27) X(28) X(29) X(30) X(31)

// ---------------- K0: repack Whh; zero stats+flags ----------------
// wq index = dir*65536 + q2*2048 + kh*1024 + j*4 + gate  (float4 units)
// value    = Whh[gate*256 + j][ (kh*32+q2)*4 .. +3 ]
__global__ __launch_bounds__(256) void k0_init(
    const float* __restrict__ WhhF, const float* __restrict__ WhhB,
    float4* __restrict__ wq, float* __restrict__ stats, int* __restrict__ flags) {
  int idx = blockIdx.x * 256 + threadIdx.x;
  if (idx < 2 * 32 * 2048) {
    int dir = idx >> 16;
    int rem = idx & 65535;
    int q2 = rem >> 11;
    int rem2 = rem & 2047;
    int kh = rem2 >> 10, j = (rem2 >> 2) & 255, gate = rem2 & 3;
    int row = gate * 256 + j;
    int col = (kh * 32 + q2) * 4;
    const float* W = (dir ? WhhB : WhhF) + (size_t)row * H + col;
    wq[idx] = make_float4(W[0], W[1], W[2], W[3]);
  }
  if (idx < 1024) stats[idx] = 0.f;
  if (idx < NPH * 32 * 16) flags[idx] = 0;
}

// ---------------- K1: proj[tc][b][g] = sum_c x[b][c][t] * Wih[g][c] + bih[g]+bhh[g] ----------------
__global__ __launch_bounds__(256) void k1_proj(
    const float* __restrict__ x,
    const float* __restrict__ WihF, const float* __restrict__ bihF, const float* __restrict__ bhhF,
    const float* __restrict__ WihB, const float* __restrict__ bihB, const float* __restrict__ bhhB,
    float* __restrict__ projF, float* __restrict__ projB, int t0f, int t0b) {
  __shared__ float Xs[16][65];
  __shared__ float Ws[16][68];
  int tid = threadIdx.x;
  int b = blockIdx.z & 15, dir = blockIdx.z >> 4;
  const float* Wih = dir ? WihB : WihF;
  const float* bih = dir ? bihB : bihF;
  const float* bhh = dir ? bhhB : bhhF;
  float* proj = dir ? projB : projF;
  int tbase = (dir ? t0b : t0f) + blockIdx.x * 64;
  int gbase = blockIdx.y * 64;
  int tx = tid & 15, ty = tid >> 4;
  float acc[4][4];
#pragma unroll
  for (int i = 0; i < 4; i++)
#pragma unroll
    for (int j = 0; j < 4; j++) acc[i][j] = 0.f;

  int lt = tid & 63, lk = tid >> 6;
  int wk = tid & 15, wg = tid >> 4;
  const float* xb = x + (size_t)b * CIN * TT;

  for (int c0 = 0; c0 < CIN; c0 += 16) {
    __syncthreads();
#pragma unroll
    for (int q = 0; q < 4; q++)
      Xs[lk + 4 * q][lt] = xb[(size_t)(c0 + lk + 4 * q) * TT + tbase + lt];
#pragma unroll
    for (int q = 0; q < 4; q++)
      Ws[wk][wg + 16 * q] = Wih[(size_t)(gbase + wg + 16 * q) * CIN + c0 + wk];
    __syncthreads();
#pragma unroll
    for (int kk = 0; kk < 16; kk++) {
      float a0 = Xs[kk][tx * 4 + 0], a1 = Xs[kk][tx * 4 + 1];
      float a2 = Xs[kk][tx * 4 + 2], a3 = Xs[kk][tx * 4 + 3];
      float b0 = Ws[kk][ty * 4 + 0], b1 = Ws[kk][ty * 4 + 1];
      float b2 = Ws[kk][ty * 4 + 2], b3 = Ws[kk][ty * 4 + 3];
      acc[0][0] += a0 * b0; acc[0][1] += a0 * b1; acc[0][2] += a0 * b2; acc[0][3] += a0 * b3;
      acc[1][0] += a1 * b0; acc[1][1] += a1 * b1; acc[1][2] += a1 * b2; acc[1][3] += a1 * b3;
      acc[2][0] += a2 * b0; acc[2][1] += a2 * b1; acc[2][2] += a2 * b2; acc[2][3] += a2 * b3;
      acc[3][0] += a3 * b0; acc[3][1] += a3 * b1; acc[3][2] += a3 * b2; acc[3][3] += a3 * b3;
    }
  }
  int g0 = gbase + ty * 4;
  float bias0 = bih[g0 + 0] + bhh[g0 + 0];
  float bias1 = bih[g0 + 1] + bhh[g0 + 1];
  float bias2 = bih[g0 + 2] + bhh[g0 + 2];
  float bias3 = bih[g0 + 3] + bhh[g0 + 3];
#pragma unroll
  for (int i = 0; i < 4; i++) {
    int tc = blockIdx.x * 64 + tx * 4 + i;
    float4 st = make_float4(acc[i][0] + bias0, acc[i][1] + bias1,
                            acc[i][2] + bias2, acc[i][3] + bias3);
    *(float4*)(proj + ((size_t)tc * BB + b) * G4H + g0) = st;
  }
}

// ---------------- K2: LSTM recurrence. 4 sibling WGs x 512 thr per (dir,b). ----------------
// Thread: gate = tid&3, kh = (tid>>2)&1, jj = tid>>3 (64 j's/WG).
// Weights: 32 named float4 in VGPRs (no array -> no SROA spill).
// Sync: RELAXED agent atomics only (no acq/rel fences -> no L2 wb/inv).
// NOTE: pv is added AFTER the kh-merge shuffle (round-3 bug: added before -> counted twice).
__global__ __launch_bounds__(512, 1) void k2_rec(
    const float4* __restrict__ wq, const float* __restrict__ projF,
    const float* __restrict__ projB, float* __restrict__ hbuf,
    float* __restrict__ hx, int* __restrict__ flags,
    float* __restrict__ hstate, float* __restrict__ cstate,
    float* __restrict__ stats, int t0f, int t0b, int first) {
  __shared__ __align__(16) float h_lds[256];
  const int tid = threadIdx.x;
  const int bx = blockIdx.x;
  const int grp = bx & 31, s = bx >> 5;     // siblings {g, g+32, g+64, g+96}
  const int dir = grp >> 4, b = grp & 15;
  const int gate = tid & 3, kh = (tid >> 2) & 1, jj = tid >> 3;
  const int j = s * 64 + jj;                // chain-local h index [0,256)
  const int row = gate * 256 + j;           // gate row [0,1024)

  const float4* wbase = wq + (size_t)dir * 65536 + kh * 1024 + (size_t)j * 4 + gate;
#define WDECL(i) const float4 w##i = wbase[(size_t)(i) * 2048];
  REP32(WDECL)
#undef WDECL

  if (tid < 256) h_lds[tid] = first ? 0.f : hstate[grp * 256 + tid];
  float c = first ? 0.f : cstate[grp * 256 + j];
  float s1 = 0.f, s2 = 0.f;
  __syncthreads();

  const float* pbase = dir ? projB : projF;
  float* hx_g = hx + grp * 512;             // double-buffered 2x256
  int* flag = flags + grp * 16;             // padded: one cache line per chain
  const int pub = (gate == 0) && (kh == 0);

  int tc0 = dir ? (CHUNK - 1) : 0;
  float pv = pbase[((size_t)tc0 * BB + b) * G4H + row];

  for (int step = 0; step < CHUNK; ++step) {
    int tc = dir ? (CHUNK - 1 - step) : step;
    int t = (dir ? t0b : t0f) + tc;

    float ax = 0.f, ay = 0.f, az = 0.f, aw = 0.f;
    const float4* h4p = ((const float4*)h_lds) + (kh << 5);
#define WFMA(i) { float4 hv = h4p[i]; ax += w##i.x * hv.x; ay += w##i.y * hv.y; \
                  az += w##i.z * hv.z; aw += w##i.w * hv.w; }
    REP32(WFMA)
#undef WFMA
    float xsum = (ax + ay) + (az + aw);
    xsum += __shfl_xor(xsum, 4, 64);        // merge k-halves (partner in-wave)
    float x = xsum + pv;                    // add proj ONCE, after the merge
    float x1 = __shfl_xor(x, 1, 64);
    float x2 = __shfl_xor(x, 2, 64);
    float x3 = __shfl_xor(x, 3, 64);
    float gi, gf, gg, go;
    if (gate == 0)      { gi = x;  gf = x1; gg = x2; go = x3; }
    else if (gate == 1) { gi = x1; gf = x;  gg = x3; go = x2; }
    else if (gate == 2) { gi = x2; gf = x3; gg = x;  go = x1; }
    else                { gi = x3; gf = x2; gg = x1; go = x;  }
    float ig = 1.f / (1.f + expf(-gi));
    float fg = 1.f / (1.f + expf(-gf));
    float gz = tanhf(gg);
    float og = 1.f / (1.f + expf(-go));
    c = fg * c + ig * gz;
    float h = og * tanhf(c);

    if (pub) {
      s1 += h; s2 += h * h;
      __hip_atomic_store(&hx_g[(step & 1) * 256 + j], h,
                         __ATOMIC_RELAXED, __HIP_MEMORY_SCOPE_AGENT);
      hbuf[((size_t)t * BB + b) * 512 + dir * 256 + j] = h;
    }
    // drain this wave's stores (ack at coherence point), then signal
    __asm__ volatile("s_waitcnt vmcnt(0) lgkmcnt(0)" ::: "memory");
    if ((tid & 63) == 0)
      __hip_atomic_fetch_add(flag, 1, __ATOMIC_RELAXED, __HIP_MEMORY_SCOPE_AGENT);

    // prefetch next step's proj (overlaps the poll)
    if (step + 1 < CHUNK) {
      int tcn = dir ? (CHUNK - 2 - step) : (step + 1);
      pv = pbase[((size_t)tcn * BB + b) * G4H + row];
    }

    int target = 32 * (step + 1);           // 4 WGs x 8 waves
    while (__hip_atomic_load(flag, __ATOMIC_RELAXED, __HIP_MEMORY_SCOPE_AGENT) < target) {}
    if (tid < 256)
      h_lds[tid] = __hip_atomic_load(&hx_g[(step & 1) * 256 + tid],
                                     __ATOMIC_RELAXED, __HIP_MEMORY_SCOPE_AGENT);
    __syncthreads();
  }

  if (tid < 256) hstate[grp * 256 + tid] = h_lds[tid];
  if (pub) {
    cstate[grp * 256 + j] = c;
    atomicAdd(&stats[dir * 256 + j], s1);
    atomicAdd(&stats[512 + dir * 256 + j], s2);
  }
}

// ---------------- K3: fold BN into linear ----------------
__global__ __launch_bounds__(512) void k3_prep(
    const float* __restrict__ stats, const float* __restrict__ gamma,
    const float* __restrict__ beta, const float* __restrict__ Wlin,
    const float* __restrict__ blin, float* __restrict__ w2, float* __restrict__ b2) {
  __shared__ float r0[512], r1[512];
  int ch = threadIdx.x;
  float mean = stats[ch] * (1.f / 32768.f);
  float var  = stats[512 + ch] * (1.f / 32768.f) - mean * mean;
  float sc = gamma[ch] * rsqrtf(var + 1e-5f);
  float w0 = Wlin[ch], w1 = Wlin[512 + ch];
  w2[ch] = w0 * sc; w2[512 + ch] = w1 * sc;
  float tt = beta[ch] - mean * sc;
  r0[ch] = w0 * tt; r1[ch] = w1 * tt;
  __syncthreads();
  for (int off = 256; off > 0; off >>= 1) {
    if (ch < off) { r0[ch] += r0[ch + off]; r1[ch] += r1[ch + off]; }
    __syncthreads();
  }
  if (ch == 0) { b2[0] = blin[0] + r0[0]; b2[1] = blin[1] + r1[0]; }
}

// ---------------- K4: posterior + gumbel hard sample; one wave per (b,t) ----------------
__global__ __launch_bounds__(256) void k4_post(
    const float* __restrict__ hbuf, const float* __restrict__ w2,
    const float* __restrict__ b2, const float* __restrict__ u,
    const float* __restrict__ e, float* __restrict__ post,
    float* __restrict__ samp) {
  int wid = (blockIdx.x * 256 + threadIdx.x) >> 6;
  int lane = threadIdx.x & 63;
  int b = wid >> 11, t = wid & 2047;
  const float* hr = hbuf + ((size_t)t * BB + b) * 512;
  int c0 = lane * 8;
  float d0 = 0.f, d1 = 0.f;
#pragma unroll
  for (int q = 0; q < 8; q++) {
    float hv = hr[c0 + q];
    d0 += w2[c0 + q] * hv;
    d1 += w2[512 + c0 + q] * hv;
  }
#pragma unroll
  for (int off = 32; off > 0; off >>= 1) {
    d0 += __shfl_xor(d0, off, 64);
    d1 += __shfl_xor(d1, off, 64);
  }
  if (lane == 0) {
    float z0 = (d0 + b2[0]) * 0.1f, z1 = (d1 + b2[1]) * 0.1f;
    float m = fmaxf(z0, z1);
    float e0 = expf(z0 - m), e1 = expf(z1 - m);
    float inv = 1.f / (e0 + e1);
    float p0 = e0 * inv, p1 = e1 * inv;
    size_t o = (size_t)b * TT + t;
    post[o * 2] = p0; post[o * 2 + 1] = p1;
    float u0 = u[o * 2], u1 = u[o * 2 + 1];
    float g0 = -logf(-logf(u0 + 1e-20f) + 1e-20f);
    float g1 = -logf(-logf(u1 + 1e-20f) + 1e-20f);
    float a0 = logf(p0) + g0, a1 = logf(p1) + g1;
    samp[o] = (a1 > a0) ? e[o] : 0.f;
  }
}

// ---------------- K5: 3x median-of-5 (reflect pad), one WG per b ----------------
#define MSWAP(a, b) { float lo_ = fminf(a, b); b = fmaxf(a, b); a = lo_; }
__global__ __launch_bounds__(256) void k5_median(
    const float* __restrict__ samp, float* __restrict__ mask) {
  __shared__ float buf[2][TT];
  int b = blockIdx.x, tid = threadIdx.x;
  for (int i = tid; i < TT; i += 256) buf[0][i] = samp[(size_t)b * TT + i];
  __syncthreads();
  int src = 0;
  for (int pass = 0; pass < 3; ++pass) {
    for (int i = tid; i < TT; i += 256) {
      float v0, v1, v2, v3, v4;
      {
        int i0 = i - 2; i0 = i0 < 0 ? -i0 : i0;
        int i1 = i - 1; i1 = i1 < 0 ? -i1 : i1;
        int i3 = i + 1; i3 = i3 > TT - 1 ? 2 * (TT - 1) - i3 : i3;
        int i4 = i + 2; i4 = i4 > TT - 1 ? 2 * (TT - 1) - i4 : i4;
        v0 = buf[src][i0]; v1 = buf[src][i1]; v2 = buf[src][i];
        v3 = buf[src][i3]; v4 = buf[src][i4];
      }
      MSWAP(v0, v1); MSWAP(v3, v4); MSWAP(v2, v4); MSWAP(v2, v3);
      MSWAP(v1, v4); MSWAP(v0, v3); MSWAP(v0, v2); MSWAP(v1, v3);
      MSWAP(v1, v2);
      buf[1 - src][i] = v2;
    }
    __syncthreads();
    src = 1 - src;
  }
  for (int i = tid; i < TT; i += 256) mask[(size_t)b * TT + i] = buf[src][i];
}

extern "C" void kernel_launch(void* const* d_in, const int* in_sizes, int n_in,
                              void* d_out, int out_size, void* d_ws, size_t ws_size,
                              hipStream_t stream) {
  const float* x    = (const float*)d_in[0];
  const float* e    = (const float*)d_in[1];
  const float* u    = (const float*)d_in[2];
  const float* WihF = (const float*)d_in[3];
  const float* WhhF = (const float*)d_in[4];
  const float* bihF = (const float*)d_in[5];
  const float* bhhF = (const float*)d_in[6];
  const float* WihB = (const float*)d_in[7];
  const float* WhhB = (const float*)d_in[8];
  const float* bihB = (const float*)d_in[9];
  const float* bhhB = (const float*)d_in[10];
  const float* gamma= (const float*)d_in[11];
  const float* beta = (const float*)d_in[12];
  const float* Wlin = (const float*)d_in[13];
  const float* blin = (const float*)d_in[14];

  float* ws = (float*)d_ws;
  float4* wq    = (float4*)(ws + OFF_WQ);
  float* projF  = ws + OFF_PROJF;
  float* projB  = ws + OFF_PROJB;
  float* hbuf   = ws + OFF_HBUF;
  float* stats  = ws + OFF_STATS;
  float* hstate = ws + OFF_HSTATE;
  float* cstate = ws + OFF_CSTATE;
  float* hx     = ws + OFF_HX;
  int*   flags  = (int*)(ws + OFF_FLAGS);
  float* w2     = ws + OFF_W2;
  float* b2     = ws + OFF_B2;
  float* samp   = ws + OFF_SAMP;

  float* post = (float*)d_out;
  float* mask = (float*)d_out + (size_t)BB * TT * 2;

  hipLaunchKernelGGL(k0_init, dim3(512), dim3(256), 0, stream,
                     WhhF, WhhB, wq, stats, flags);
  for (int p = 0; p < NPH; ++p) {
    int t0f = p * CHUNK;
    int t0b = (NPH - 1 - p) * CHUNK;
    hipLaunchKernelGGL(k1_proj, dim3(4, 16, 32), dim3(256), 0, stream,
                       x, WihF, bihF, bhhF, WihB, bihB, bhhB, projF, projB, t0f, t0b);
    hipLaunchKernelGGL(k2_rec, dim3(128), dim3(512), 0, stream,
                       wq, projF, projB, hbuf, hx, flags + p * 32 * 16,
                       hstate, cstate, stats, t0f, t0b, p == 0 ? 1 : 0);
  }
  hipLaunchKernelGGL(k3_prep, dim3(1), dim3(512), 0, stream,
                     stats, gamma, beta, Wlin, blin, w2, b2);
  hipLaunchKernelGGL(k4_post, dim3(8192), dim3(256), 0, stream,
                     hbuf, w2, b2, u, e, post, samp);
  hipLaunchKernelGGL(k5_median, dim3(16), dim3(256), 0, stream, samp, mask);
}

// Round 5
// 7018.451 us; speedup vs baseline: 2.6926x; 1.7242x over previous
//
#include <hip/hip_runtime.h>
#include <math.h>

#define H    256
#define G4H  1024
#define CIN  512
#define BB   16
#define TT   2048
#define CHUNK 256
#define NPH  8   // TT/CHUNK

// ---- workspace layout (in floats) ----
#define OFF_WQ      ((size_t)0)                        // 131072 float4 = 524288 floats
#define OFF_PROJF   ((size_t)524288)                   // 256*16*1024
#define OFF_PROJB   (OFF_PROJF + (size_t)4194304)
#define OFF_HBUF    (OFF_PROJB + (size_t)4194304)      // 2048*16*512
#define OFF_STATS   (OFF_HBUF  + (size_t)16777216)     // 1024
#define OFF_HSTATE  (OFF_STATS + (size_t)1024)         // 32*256
#define OFF_CSTATE  (OFF_HSTATE + (size_t)8192)        // 32*256
#define OFF_HX      (OFF_CSTATE + (size_t)8192)        // 32*2*256
#define OFF_FLAGS   (OFF_HX + (size_t)16384)           // NPH*32*16 ints = 4096
#define OFF_W2      (OFF_FLAGS + (size_t)4096)         // 1024
#define OFF_B2      (OFF_W2 + (size_t)1024)            // 16
#define OFF_SAMP    (OFF_B2 + (size_t)16)              // 16*2048

#define REP32(X) X(0) X(1) X(2) X(3) X(4) X(5) X(6) X(7) X(8) X(9) X(10) X(11) \
  X(12) X(13) X(14) X(15) X(16) X(17) X(18) X(19) X(20) X(21) X(22) X(23) \
  X(24) X(25) X(26) X(27) X(28) X(29) X(30) X(31)

// ---------------- K0: repack Whh; zero stats+flags ----------------
// wq float4 index = (((dir*2 + kh)*32 + q)*4 + gate)*256 + j
// value = Whh_dir[gate*256 + j][kh*128 + q*4 .. +3]
__global__ __launch_bounds__(256) void k0_init(
    const float* __restrict__ WhhF, const float* __restrict__ WhhB,
    float4* __restrict__ wq, float* __restrict__ stats, int* __restrict__ flags) {
  int idx = blockIdx.x * 256 + threadIdx.x;
  if (idx < 131072) {
    int j = idx & 255, gate = (idx >> 8) & 3, q = (idx >> 10) & 31;
    int kh = (idx >> 15) & 1, dir = idx >> 16;
    int row = gate * 256 + j;
    int col = kh * 128 + q * 4;
    const float* W = (dir ? WhhB : WhhF) + (size_t)row * H + col;
    wq[idx] = make_float4(W[0], W[1], W[2], W[3]);
  }
  if (idx < 1024) stats[idx] = 0.f;
  if (idx < NPH * 32 * 16) flags[idx] = 0;
}

// ---------------- K1: proj[tc][b][g] = sum_c x[b][c][t] * Wih[g][c] + bih[g]+bhh[g] ----------------
__global__ __launch_bounds__(256) void k1_proj(
    const float* __restrict__ x,
    const float* __restrict__ WihF, const float* __restrict__ bihF, const float* __restrict__ bhhF,
    const float* __restrict__ WihB, const float* __restrict__ bihB, const float* __restrict__ bhhB,
    float* __restrict__ projF, float* __restrict__ projB, int t0f, int t0b) {
  __shared__ float Xs[16][65];
  __shared__ float Ws[16][68];
  int tid = threadIdx.x;
  int b = blockIdx.z & 15, dir = blockIdx.z >> 4;
  const float* Wih = dir ? WihB : WihF;
  const float* bih = dir ? bihB : bihF;
  const float* bhh = dir ? bhhB : bhhF;
  float* proj = dir ? projB : projF;
  int tbase = (dir ? t0b : t0f) + blockIdx.x * 64;
  int gbase = blockIdx.y * 64;
  int tx = tid & 15, ty = tid >> 4;
  float acc[4][4];
#pragma unroll
  for (int i = 0; i < 4; i++)
#pragma unroll
    for (int j = 0; j < 4; j++) acc[i][j] = 0.f;

  int lt = tid & 63, lk = tid >> 6;
  int wk = tid & 15, wg = tid >> 4;
  const float* xb = x + (size_t)b * CIN * TT;

  for (int c0 = 0; c0 < CIN; c0 += 16) {
    __syncthreads();
#pragma unroll
    for (int q = 0; q < 4; q++)
      Xs[lk + 4 * q][lt] = xb[(size_t)(c0 + lk + 4 * q) * TT + tbase + lt];
#pragma unroll
    for (int q = 0; q < 4; q++)
      Ws[wk][wg + 16 * q] = Wih[(size_t)(gbase + wg + 16 * q) * CIN + c0 + wk];
    __syncthreads();
#pragma unroll
    for (int kk = 0; kk < 16; kk++) {
      float a0 = Xs[kk][tx * 4 + 0], a1 = Xs[kk][tx * 4 + 1];
      float a2 = Xs[kk][tx * 4 + 2], a3 = Xs[kk][tx * 4 + 3];
      float b0 = Ws[kk][ty * 4 + 0], b1 = Ws[kk][ty * 4 + 1];
      float b2 = Ws[kk][ty * 4 + 2], b3 = Ws[kk][ty * 4 + 3];
      acc[0][0] += a0 * b0; acc[0][1] += a0 * b1; acc[0][2] += a0 * b2; acc[0][3] += a0 * b3;
      acc[1][0] += a1 * b0; acc[1][1] += a1 * b1; acc[1][2] += a1 * b2; acc[1][3] += a1 * b3;
      acc[2][0] += a2 * b0; acc[2][1] += a2 * b1; acc[2][2] += a2 * b2; acc[2][3] += a2 * b3;
      acc[3][0] += a3 * b0; acc[3][1] += a3 * b1; acc[3][2] += a3 * b2; acc[3][3] += a3 * b3;
    }
  }
  int g0 = gbase + ty * 4;
  float bias0 = bih[g0 + 0] + bhh[g0 + 0];
  float bias1 = bih[g0 + 1] + bhh[g0 + 1];
  float bias2 = bih[g0 + 2] + bhh[g0 + 2];
  float bias3 = bih[g0 + 3] + bhh[g0 + 3];
#pragma unroll
  for (int i = 0; i < 4; i++) {
    int tc = blockIdx.x * 64 + tx * 4 + i;
    float4 st = make_float4(acc[i][0] + bias0, acc[i][1] + bias1,
                            acc[i][2] + bias2, acc[i][3] + bias3);
    *(float4*)(proj + ((size_t)tc * BB + b) * G4H + g0) = st;
  }
}

// ---------------- K2: LSTM recurrence. 4 sibling WGs x 512 thr per (dir,b). ----------------
// Wave-major split: wave w (0..7): kh = w>>2, gate = w&3, lane l = row j offset.
// All lanes of a wave read the SAME h4 address -> pure LDS broadcast, no conflicts.
// Weights pinned into VGPRs via empty asm (cannot be rematerialized/sunk).
__global__ __launch_bounds__(512, 2) void k2_rec(
    const float4* __restrict__ wq, const float* __restrict__ projF,
    const float* __restrict__ projB, float* __restrict__ hbuf,
    float* __restrict__ hx, int* __restrict__ flags,
    float* __restrict__ hstate, float* __restrict__ cstate,
    float* __restrict__ stats, int t0f, int t0b, int first) {
  __shared__ __align__(16) float h_lds[256];
  __shared__ float pbuf[512];
  const int tid = threadIdx.x;
  const int l = tid & 63, w = tid >> 6;
  const int kh = w >> 2, gate = w & 3;
  const int bx = blockIdx.x;
  const int grp = bx & 31, s = bx >> 5;     // siblings {g, g+32, g+64, g+96} (same XCD mod 8)
  const int dir = grp >> 4, b = grp & 15;
  const int j = s * 64 + l;                 // chain-local h index [0,256)
  const int row = gate * 256 + j;           // gate row [0,1024)

  // weight base: q-stride = 4*256 = 1024 float4
  const float4* wbase = wq + (size_t)(((dir * 2 + kh) * 32 * 4 + gate)) * 256 + j;
#define WDECL(i) float wx##i, wy##i, wz##i, ww##i; \
  { float4 t_ = wbase[(size_t)(i) * 1024]; \
    wx##i = t_.x; wy##i = t_.y; wz##i = t_.z; ww##i = t_.w; } \
  asm volatile("" : "+v"(wx##i), "+v"(wy##i), "+v"(wz##i), "+v"(ww##i));
  REP32(WDECL)
#undef WDECL

  if (tid < 256) h_lds[tid] = first ? 0.f : hstate[grp * 256 + tid];
  float c = 0.f, s1 = 0.f, s2 = 0.f;
  if (w == 0 && !first) c = cstate[grp * 256 + j];
  __syncthreads();

  const float* pbase = dir ? projB : projF;
  float* hx_g = hx + grp * 512;             // double-buffered 2x256
  int* flag = flags + grp * 16;             // padded: one cache line per chain

  int tc0 = dir ? (CHUNK - 1) : 0;
  float pv = 0.f;
  if (kh == 0) pv = pbase[((size_t)tc0 * BB + b) * G4H + row];

  for (int step = 0; step < CHUNK; ++step) {
    int tc = dir ? (CHUNK - 1 - step) : step;
    int t = (dir ? t0b : t0f) + tc;

    float acc = (kh == 0) ? pv : 0.f;
    const float4* h4p = ((const float4*)h_lds) + (kh << 5);
#define WFMA(i) { float4 hv = h4p[i]; \
    acc += wx##i * hv.x + wy##i * hv.y + wz##i * hv.z + ww##i * hv.w; }
    REP32(WFMA)
#undef WFMA
    pbuf[tid] = acc;
    __syncthreads();                         // B1: pbuf ready; all h_lds reads done

    if (w == 0) {
      float gi = pbuf[0 * 64 + l] + pbuf[4 * 64 + l];
      float gf = pbuf[1 * 64 + l] + pbuf[5 * 64 + l];
      float gg = pbuf[2 * 64 + l] + pbuf[6 * 64 + l];
      float go = pbuf[3 * 64 + l] + pbuf[7 * 64 + l];
      float ig = 1.f / (1.f + expf(-gi));
      float fg = 1.f / (1.f + expf(-gf));
      float gz = tanhf(gg);
      float og = 1.f / (1.f + expf(-go));
      c = fg * c + ig * gz;
      float h = og * tanhf(c);
      s1 += h; s2 += h * h;
      hbuf[((size_t)t * BB + b) * 512 + dir * 256 + j] = h;
      __hip_atomic_store(&hx_g[(step & 1) * 256 + j], h,
                         __ATOMIC_RELAXED, __HIP_MEMORY_SCOPE_AGENT);
      // drain h stores to coherence point, then signal (this wave only)
      __asm__ volatile("s_waitcnt vmcnt(0) lgkmcnt(0)" ::: "memory");
      if (tid == 0)
        __hip_atomic_fetch_add(flag, 1, __ATOMIC_RELAXED, __HIP_MEMORY_SCOPE_AGENT);
    }

    // prefetch next step's proj AFTER the publish (vmcnt must not wait on it)
    if (kh == 0 && step + 1 < CHUNK) {
      int tcn = dir ? (CHUNK - 2 - step) : (step + 1);
      pv = pbase[((size_t)tcn * BB + b) * G4H + row];
    }

    if (tid == 0) {                          // single poller per WG
      int target = 4 * (step + 1);
      while (__hip_atomic_load(flag, __ATOMIC_RELAXED, __HIP_MEMORY_SCOPE_AGENT) < target) {}
    }
    __syncthreads();                         // B2: flag reached
    if (tid < 256)
      h_lds[tid] = __hip_atomic_load(&hx_g[(step & 1) * 256 + tid],
                                     __ATOMIC_RELAXED, __HIP_MEMORY_SCOPE_AGENT);
    __syncthreads();                         // B3: h_lds ready
  }

  if (tid < 256) hstate[grp * 256 + tid] = h_lds[tid];
  if (w == 0) {
    cstate[grp * 256 + j] = c;
    atomicAdd(&stats[dir * 256 + j], s1);
    atomicAdd(&stats[512 + dir * 256 + j], s2);
  }
}

// ---------------- K3: fold BN into linear ----------------
__global__ __launch_bounds__(512) void k3_prep(
    const float* __restrict__ stats, const float* __restrict__ gamma,
    const float* __restrict__ beta, const float* __restrict__ Wlin,
    const float* __restrict__ blin, float* __restrict__ w2, float* __restrict__ b2) {
  __shared__ float r0[512], r1[512];
  int ch = threadIdx.x;
  float mean = stats[ch] * (1.f / 32768.f);
  float var  = stats[512 + ch] * (1.f / 32768.f) - mean * mean;
  float sc = gamma[ch] * rsqrtf(var + 1e-5f);
  float w0 = Wlin[ch], w1 = Wlin[512 + ch];
  w2[ch] = w0 * sc; w2[512 + ch] = w1 * sc;
  float tt = beta[ch] - mean * sc;
  r0[ch] = w0 * tt; r1[ch] = w1 * tt;
  __syncthreads();
  for (int off = 256; off > 0; off >>= 1) {
    if (ch < off) { r0[ch] += r0[ch + off]; r1[ch] += r1[ch + off]; }
    __syncthreads();
  }
  if (ch == 0) { b2[0] = blin[0] + r0[0]; b2[1] = blin[1] + r1[0]; }
}

// ---------------- K4: posterior + gumbel hard sample; one wave per (b,t) ----------------
__global__ __launch_bounds__(256) void k4_post(
    const float* __restrict__ hbuf, const float* __restrict__ w2,
    const float* __restrict__ b2, const float* __restrict__ u,
    const float* __restrict__ e, float* __restrict__ post,
    float* __restrict__ samp) {
  int wid = (blockIdx.x * 256 + threadIdx.x) >> 6;
  int lane = threadIdx.x & 63;
  int b = wid >> 11, t = wid & 2047;
  const float* hr = hbuf + ((size_t)t * BB + b) * 512;
  int c0 = lane * 8;
  float d0 = 0.f, d1 = 0.f;
#pragma unroll
  for (int q = 0; q < 8; q++) {
    float hv = hr[c0 + q];
    d0 += w2[c0 + q] * hv;
    d1 += w2[512 + c0 + q] * hv;
  }
#pragma unroll
  for (int off = 32; off > 0; off >>= 1) {
    d0 += __shfl_xor(d0, off, 64);
    d1 += __shfl_xor(d1, off, 64);
  }
  if (lane == 0) {
    float z0 = (d0 + b2[0]) * 0.1f, z1 = (d1 + b2[1]) * 0.1f;
    float m = fmaxf(z0, z1);
    float e0 = expf(z0 - m), e1 = expf(z1 - m);
    float inv = 1.f / (e0 + e1);
    float p0 = e0 * inv, p1 = e1 * inv;
    size_t o = (size_t)b * TT + t;
    post[o * 2] = p0; post[o * 2 + 1] = p1;
    float u0 = u[o * 2], u1 = u[o * 2 + 1];
    float g0 = -logf(-logf(u0 + 1e-20f) + 1e-20f);
    float g1 = -logf(-logf(u1 + 1e-20f) + 1e-20f);
    float a0 = logf(p0) + g0, a1 = logf(p1) + g1;
    samp[o] = (a1 > a0) ? e[o] : 0.f;
  }
}

// ---------------- K5: 3x median-of-5 (reflect pad), one WG per b ----------------
#define MSWAP(a, b) { float lo_ = fminf(a, b); b = fmaxf(a, b); a = lo_; }
__global__ __launch_bounds__(256) void k5_median(
    const float* __restrict__ samp, float* __restrict__ mask) {
  __shared__ float buf[2][TT];
  int b = blockIdx.x, tid = threadIdx.x;
  for (int i = tid; i < TT; i += 256) buf[0][i] = samp[(size_t)b * TT + i];
  __syncthreads();
  int src = 0;
  for (int pass = 0; pass < 3; ++pass) {
    for (int i = tid; i < TT; i += 256) {
      float v0, v1, v2, v3, v4;
      {
        int i0 = i - 2; i0 = i0 < 0 ? -i0 : i0;
        int i1 = i - 1; i1 = i1 < 0 ? -i1 : i1;
        int i3 = i + 1; i3 = i3 > TT - 1 ? 2 * (TT - 1) - i3 : i3;
        int i4 = i + 2; i4 = i4 > TT - 1 ? 2 * (TT - 1) - i4 : i4;
        v0 = buf[src][i0]; v1 = buf[src][i1]; v2 = buf[src][i];
        v3 = buf[src][i3]; v4 = buf[src][i4];
      }
      MSWAP(v0, v1); MSWAP(v3, v4); MSWAP(v2, v4); MSWAP(v2, v3);
      MSWAP(v1, v4); MSWAP(v0, v3); MSWAP(v0, v2); MSWAP(v1, v3);
      MSWAP(v1, v2);
      buf[1 - src][i] = v2;
    }
    __syncthreads();
    src = 1 - src;
  }
  for (int i = tid; i < TT; i += 256) mask[(size_t)b * TT + i] = buf[src][i];
}

extern "C" void kernel_launch(void* const* d_in, const int* in_sizes, int n_in,
                              void* d_out, int out_size, void* d_ws, size_t ws_size,
                              hipStream_t stream) {
  const float* x    = (const float*)d_in[0];
  const float* e    = (const float*)d_in[1];
  const float* u    = (const float*)d_in[2];
  const float* WihF = (const float*)d_in[3];
  const float* WhhF = (const float*)d_in[4];
  const float* bihF = (const float*)d_in[5];
  const float* bhhF = (const float*)d_in[6];
  const float* WihB = (const float*)d_in[7];
  const float* WhhB = (const float*)d_in[8];
  const float* bihB = (const float*)d_in[9];
  const float* bhhB = (const float*)d_in[10];
  const float* gamma= (const float*)d_in[11];
  const float* beta = (const float*)d_in[12];
  const float* Wlin = (const float*)d_in[13];
  const float* blin = (const float*)d_in[14];

  float* ws = (float*)d_ws;
  float4* wq    = (float4*)(ws + OFF_WQ);
  float* projF  = ws + OFF_PROJF;
  float* projB  = ws + OFF_PROJB;
  float* hbuf   = ws + OFF_HBUF;
  float* stats  = ws + OFF_STATS;
  float* hstate = ws + OFF_HSTATE;
  float* cstate = ws + OFF_CSTATE;
  float* hx     = ws + OFF_HX;
  int*   flags  = (int*)(ws + OFF_FLAGS);
  float* w2     = ws + OFF_W2;
  float* b2     = ws + OFF_B2;
  float* samp   = ws + OFF_SAMP;

  float* post = (float*)d_out;
  float* mask = (float*)d_out + (size_t)BB * TT * 2;

  hipLaunchKernelGGL(k0_init, dim3(512), dim3(256), 0, stream,
                     WhhF, WhhB, wq, stats, flags);
  for (int p = 0; p < NPH; ++p) {
    int t0f = p * CHUNK;
    int t0b = (NPH - 1 - p) * CHUNK;
    hipLaunchKernelGGL(k1_proj, dim3(4, 16, 32), dim3(256), 0, stream,
                       x, WihF, bihF, bhhF, WihB, bihB, bhhB, projF, projB, t0f, t0b);
    hipLaunchKernelGGL(k2_rec, dim3(128), dim3(512), 0, stream,
                       wq, projF, projB, hbuf, hx, flags + p * 32 * 16,
                       hstate, cstate, stats, t0f, t0b, p == 0 ? 1 : 0);
  }
  hipLaunchKernelGGL(k3_prep, dim3(1), dim3(512), 0, stream,
                     stats, gamma, beta, Wlin, blin, w2, b2);
  hipLaunchKernelGGL(k4_post, dim3(8192), dim3(256), 0, stream,
                     hbuf, w2, b2, u, e, post, samp);
  hipLaunchKernelGGL(k5_median, dim3(16), dim3(256), 0, stream, samp, mask);
}

// Round 6
// 6573.564 us; speedup vs baseline: 2.8748x; 1.0677x over previous
//
#include <hip/hip_runtime.h>
#include <math.h>

#define H    256
#define G4H  1024
#define CIN  512
#define BB   16
#define TT   2048
#define CHUNK 256
#define NPH  8   // TT/CHUNK

// ---- workspace layout (in floats) ----
#define OFF_WQ      ((size_t)0)                        // 131072 float4 = 524288 floats
#define OFF_PROJF   ((size_t)524288)                   // 256*16*1024
#define OFF_PROJB   (OFF_PROJF + (size_t)4194304)
#define OFF_HBUF    (OFF_PROJB + (size_t)4194304)      // 2048*16*512
#define OFF_STATS   (OFF_HBUF  + (size_t)16777216)     // 1024
#define OFF_HSTATE  (OFF_STATS + (size_t)1024)         // 32*256
#define OFF_CSTATE  (OFF_HSTATE + (size_t)8192)        // 32*256
#define OFF_HX      (OFF_CSTATE + (size_t)8192)        // 32*2*256
#define OFF_FLAGS   (OFF_HX + (size_t)16384)           // 32 chains * 8 slots * 16 ints = 4096
#define OFF_W2      (OFF_FLAGS + (size_t)4096)         // 1024
#define OFF_B2      (OFF_W2 + (size_t)1024)            // 16
#define OFF_SAMP    (OFF_B2 + (size_t)16)              // 16*2048

#define REP16(X) X(0) X(1) X(2) X(3) X(4) X(5) X(6) X(7) X(8) X(9) X(10) X(11) \
  X(12) X(13) X(14) X(15)

// ---------------- K0: repack Whh; zero stats+epochs ----------------
// wq float4 idx = (dir*4+kq)*16384 + q*1024 + gate*256 + s*32 + jl
// value = Whh_dir[gate*256 + s*32 + jl][kq*64 + q*4 .. +3]
__global__ __launch_bounds__(256) void k0_init(
    const float* __restrict__ WhhF, const float* __restrict__ WhhB,
    float4* __restrict__ wq, float* __restrict__ stats, int* __restrict__ flags) {
  int idx = blockIdx.x * 256 + threadIdx.x;
  if (idx < 131072) {
    int jl = idx & 31, s = (idx >> 5) & 7, gate = (idx >> 8) & 3;
    int q = (idx >> 10) & 15, kq = (idx >> 14) & 3, dir = idx >> 16;
    int row = gate * 256 + s * 32 + jl;
    int col = kq * 64 + q * 4;
    const float* W = (dir ? WhhB : WhhF) + (size_t)row * H + col;
    wq[idx] = make_float4(W[0], W[1], W[2], W[3]);
  }
  if (idx < 1024) stats[idx] = 0.f;
  if (idx < 4096) flags[idx] = 0;   // epochs: zeroed ONCE; absolute step counts
}

// ---------------- K1: proj[tc][b][g] = sum_c x[b][c][t] * Wih[g][c] + bih[g]+bhh[g] ----------------
__global__ __launch_bounds__(256) void k1_proj(
    const float* __restrict__ x,
    const float* __restrict__ WihF, const float* __restrict__ bihF, const float* __restrict__ bhhF,
    const float* __restrict__ WihB, const float* __restrict__ bihB, const float* __restrict__ bhhB,
    float* __restrict__ projF, float* __restrict__ projB, int t0f, int t0b) {
  __shared__ float Xs[16][65];
  __shared__ float Ws[16][68];
  int tid = threadIdx.x;
  int b = blockIdx.z & 15, dir = blockIdx.z >> 4;
  const float* Wih = dir ? WihB : WihF;
  const float* bih = dir ? bihB : bihF;
  const float* bhh = dir ? bhhB : bhhF;
  float* proj = dir ? projB : projF;
  int tbase = (dir ? t0b : t0f) + blockIdx.x * 64;
  int gbase = blockIdx.y * 64;
  int tx = tid & 15, ty = tid >> 4;
  float acc[4][4];
#pragma unroll
  for (int i = 0; i < 4; i++)
#pragma unroll
    for (int j = 0; j < 4; j++) acc[i][j] = 0.f;

  int lt = tid & 63, lk = tid >> 6;
  int wk = tid & 15, wg = tid >> 4;
  const float* xb = x + (size_t)b * CIN * TT;

  for (int c0 = 0; c0 < CIN; c0 += 16) {
    __syncthreads();
#pragma unroll
    for (int q = 0; q < 4; q++)
      Xs[lk + 4 * q][lt] = xb[(size_t)(c0 + lk + 4 * q) * TT + tbase + lt];
#pragma unroll
    for (int q = 0; q < 4; q++)
      Ws[wk][wg + 16 * q] = Wih[(size_t)(gbase + wg + 16 * q) * CIN + c0 + wk];
    __syncthreads();
#pragma unroll
    for (int kk = 0; kk < 16; kk++) {
      float a0 = Xs[kk][tx * 4 + 0], a1 = Xs[kk][tx * 4 + 1];
      float a2 = Xs[kk][tx * 4 + 2], a3 = Xs[kk][tx * 4 + 3];
      float b0 = Ws[kk][ty * 4 + 0], b1 = Ws[kk][ty * 4 + 1];
      float b2 = Ws[kk][ty * 4 + 2], b3 = Ws[kk][ty * 4 + 3];
      acc[0][0] += a0 * b0; acc[0][1] += a0 * b1; acc[0][2] += a0 * b2; acc[0][3] += a0 * b3;
      acc[1][0] += a1 * b0; acc[1][1] += a1 * b1; acc[1][2] += a1 * b2; acc[1][3] += a1 * b3;
      acc[2][0] += a2 * b0; acc[2][1] += a2 * b1; acc[2][2] += a2 * b2; acc[2][3] += a2 * b3;
      acc[3][0] += a3 * b0; acc[3][1] += a3 * b1; acc[3][2] += a3 * b2; acc[3][3] += a3 * b3;
    }
  }
  int g0 = gbase + ty * 4;
  float bias0 = bih[g0 + 0] + bhh[g0 + 0];
  float bias1 = bih[g0 + 1] + bhh[g0 + 1];
  float bias2 = bih[g0 + 2] + bhh[g0 + 2];
  float bias3 = bih[g0 + 3] + bhh[g0 + 3];
#pragma unroll
  for (int i = 0; i < 4; i++) {
    int tc = blockIdx.x * 64 + tx * 4 + i;
    float4 st = make_float4(acc[i][0] + bias0, acc[i][1] + bias1,
                            acc[i][2] + bias2, acc[i][3] + bias3);
    *(float4*)(proj + ((size_t)tc * BB + b) * G4H + g0) = st;
  }
}

// ---------------- K2: LSTM recurrence. 8 sibling WGs x 512 thr per (dir,b). ----------------
// Thread: jl = tid&31, gate = (tid>>5)&3, kq = tid>>7. Owns gate-row (gate*256+32s+jl),
// K-slice kq*64..+63 -> 16 float4 pinned in VGPRs. h reads are wave-uniform (broadcast).
// Sync: per-WG padded epoch words (absolute step count), parallel poll by wave0 lanes 0..7.
__global__ __launch_bounds__(512, 2) void k2_rec(
    const float4* __restrict__ wq, const float* __restrict__ projF,
    const float* __restrict__ projB, float* __restrict__ hbuf,
    float* __restrict__ hx, int* __restrict__ flags,
    float* __restrict__ hstate, float* __restrict__ cstate,
    float* __restrict__ stats, int t0f, int t0b, int first, int ebase) {
  __shared__ __align__(16) float h_lds[256];
  __shared__ float pbuf[512];
  const int tid = threadIdx.x;
  const int l = tid & 63, w = tid >> 6;
  const int jl = tid & 31, gate = (tid >> 5) & 3, kq = tid >> 7;
  const int bx = blockIdx.x;
  const int grp = bx & 31, s = bx >> 5;     // 8 siblings: {g, g+32, ..., g+224}
  const int dir = grp >> 4, b = grp & 15;
  const int row = gate * 256 + s * 32 + jl; // gate row [0,1024)

  const float4* wbase = wq + (size_t)(dir * 4 + kq) * 16384 + gate * 256 + s * 32 + jl;
#define WDECL(i) float wx##i, wy##i, wz##i, ww##i; \
  { float4 t_ = wbase[(size_t)(i) * 1024]; \
    wx##i = t_.x; wy##i = t_.y; wz##i = t_.z; ww##i = t_.w; } \
  asm volatile("" : "+v"(wx##i), "+v"(wy##i), "+v"(wz##i), "+v"(ww##i));
  REP16(WDECL)
#undef WDECL

  if (tid < 256) h_lds[tid] = first ? 0.f : hstate[grp * 256 + tid];
  float c = 0.f, s1 = 0.f, s2 = 0.f;
  if (w == 0 && l < 32 && !first) c = cstate[grp * 256 + s * 32 + l];
  __syncthreads();

  const float* pbase = dir ? projB : projF;
  float* hx_g = hx + grp * 512;             // double-buffered 2x256
  int* eb = flags + grp * 128;              // 8 epoch slots, 64B apart

  int tc0 = dir ? (CHUNK - 1) : 0;
  float pv = 0.f;
  if (kq == 0) pv = pbase[((size_t)tc0 * BB + b) * G4H + row];

  for (int step = 0; step < CHUNK; ++step) {
    int tc = dir ? (CHUNK - 1 - step) : step;
    int t = (dir ? t0b : t0f) + tc;
    int target = ebase + step + 1;          // absolute epoch

    float acc = (kq == 0) ? pv : 0.f;
    const float4* h4p = ((const float4*)h_lds) + (kq << 4);
#define WFMA(i) { float4 hv = h4p[i]; \
    acc += wx##i * hv.x + wy##i * hv.y + wz##i * hv.z + ww##i * hv.w; }
    REP16(WFMA)
#undef WFMA
    pbuf[tid] = acc;
    __syncthreads();                         // B1: pbuf ready; all h_lds reads done

    if (w == 0 && l < 32) {
      float gi = pbuf[l]       + pbuf[128 + l]       + pbuf[256 + l]       + pbuf[384 + l];
      float gf = pbuf[32 + l]  + pbuf[160 + l]       + pbuf[288 + l]       + pbuf[416 + l];
      float gg = pbuf[64 + l]  + pbuf[192 + l]       + pbuf[320 + l]       + pbuf[448 + l];
      float go = pbuf[96 + l]  + pbuf[224 + l]       + pbuf[352 + l]       + pbuf[480 + l];
      float ig = 1.f / (1.f + expf(-gi));
      float fg = 1.f / (1.f + expf(-gf));
      float gz = tanhf(gg);
      float og = 1.f / (1.f + expf(-go));
      c = fg * c + ig * gz;
      float h = og * tanhf(c);
      s1 += h; s2 += h * h;
      int j = s * 32 + l;
      hbuf[((size_t)t * BB + b) * 512 + dir * 256 + j] = h;
      __hip_atomic_store(&hx_g[(step & 1) * 256 + j], h,
                         __ATOMIC_RELAXED, __HIP_MEMORY_SCOPE_AGENT);
      __asm__ volatile("s_waitcnt vmcnt(0) lgkmcnt(0)" ::: "memory");
      if (l == 0)
        __hip_atomic_store(&eb[s * 16], target,
                           __ATOMIC_RELAXED, __HIP_MEMORY_SCOPE_AGENT);
    }

    // prefetch next step's proj (after publish; overlaps the poll)
    if (kq == 0 && step + 1 < CHUNK) {
      int tcn = dir ? (CHUNK - 2 - step) : (step + 1);
      pv = pbase[((size_t)tcn * BB + b) * G4H + row];
    }

    if (w == 0) {                            // parallel poll: lanes 0..7, one epoch each
      for (;;) {
        int ep = target;
        if (l < 8)
          ep = __hip_atomic_load(&eb[l * 16], __ATOMIC_RELAXED, __HIP_MEMORY_SCOPE_AGENT);
        if (__all(ep >= target)) break;
      }
    }
    __syncthreads();                         // B2: all epochs reached
    if (tid < 256)
      h_lds[tid] = __hip_atomic_load(&hx_g[(step & 1) * 256 + tid],
                                     __ATOMIC_RELAXED, __HIP_MEMORY_SCOPE_AGENT);
    __syncthreads();                         // B3: h_lds ready
  }

  if (tid < 256) hstate[grp * 256 + tid] = h_lds[tid];
  if (w == 0 && l < 32) {
    cstate[grp * 256 + s * 32 + l] = c;
    atomicAdd(&stats[dir * 256 + s * 32 + l], s1);
    atomicAdd(&stats[512 + dir * 256 + s * 32 + l], s2);
  }
}

// ---------------- K3: fold BN into linear ----------------
__global__ __launch_bounds__(512) void k3_prep(
    const float* __restrict__ stats, const float* __restrict__ gamma,
    const float* __restrict__ beta, const float* __restrict__ Wlin,
    const float* __restrict__ blin, float* __restrict__ w2, float* __restrict__ b2) {
  __shared__ float r0[512], r1[512];
  int ch = threadIdx.x;
  float mean = stats[ch] * (1.f / 32768.f);
  float var  = stats[512 + ch] * (1.f / 32768.f) - mean * mean;
  float sc = gamma[ch] * rsqrtf(var + 1e-5f);
  float w0 = Wlin[ch], w1 = Wlin[512 + ch];
  w2[ch] = w0 * sc; w2[512 + ch] = w1 * sc;
  float tt = beta[ch] - mean * sc;
  r0[ch] = w0 * tt; r1[ch] = w1 * tt;
  __syncthreads();
  for (int off = 256; off > 0; off >>= 1) {
    if (ch < off) { r0[ch] += r0[ch + off]; r1[ch] += r1[ch + off]; }
    __syncthreads();
  }
  if (ch == 0) { b2[0] = blin[0] + r0[0]; b2[1] = blin[1] + r1[0]; }
}

// ---------------- K4: posterior + gumbel hard sample; one wave per (b,t) ----------------
__global__ __launch_bounds__(256) void k4_post(
    const float* __restrict__ hbuf, const float* __restrict__ w2,
    const float* __restrict__ b2, const float* __restrict__ u,
    const float* __restrict__ e, float* __restrict__ post,
    float* __restrict__ samp) {
  int wid = (blockIdx.x * 256 + threadIdx.x) >> 6;
  int lane = threadIdx.x & 63;
  int b = wid >> 11, t = wid & 2047;
  const float* hr = hbuf + ((size_t)t * BB + b) * 512;
  int c0 = lane * 8;
  float d0 = 0.f, d1 = 0.f;
#pragma unroll
  for (int q = 0; q < 8; q++) {
    float hv = hr[c0 + q];
    d0 += w2[c0 + q] * hv;
    d1 += w2[512 + c0 + q] * hv;
  }
#pragma unroll
  for (int off = 32; off > 0; off >>= 1) {
    d0 += __shfl_xor(d0, off, 64);
    d1 += __shfl_xor(d1, off, 64);
  }
  if (lane == 0) {
    float z0 = (d0 + b2[0]) * 0.1f, z1 = (d1 + b2[1]) * 0.1f;
    float m = fmaxf(z0, z1);
    float e0 = expf(z0 - m), e1 = expf(z1 - m);
    float inv = 1.f / (e0 + e1);
    float p0 = e0 * inv, p1 = e1 * inv;
    size_t o = (size_t)b * TT + t;
    post[o * 2] = p0; post[o * 2 + 1] = p1;
    float u0 = u[o * 2], u1 = u[o * 2 + 1];
    float g0 = -logf(-logf(u0 + 1e-20f) + 1e-20f);
    float g1 = -logf(-logf(u1 + 1e-20f) + 1e-20f);
    float a0 = logf(p0) + g0, a1 = logf(p1) + g1;
    samp[o] = (a1 > a0) ? e[o] : 0.f;
  }
}

// ---------------- K5: 3x median-of-5 (reflect pad), one WG per b ----------------
#define MSWAP(a, b) { float lo_ = fminf(a, b); b = fmaxf(a, b); a = lo_; }
__global__ __launch_bounds__(256) void k5_median(
    const float* __restrict__ samp, float* __restrict__ mask) {
  __shared__ float buf[2][TT];
  int b = blockIdx.x, tid = threadIdx.x;
  for (int i = tid; i < TT; i += 256) buf[0][i] = samp[(size_t)b * TT + i];
  __syncthreads();
  int src = 0;
  for (int pass = 0; pass < 3; ++pass) {
    for (int i = tid; i < TT; i += 256) {
      float v0, v1, v2, v3, v4;
      {
        int i0 = i - 2; i0 = i0 < 0 ? -i0 : i0;
        int i1 = i - 1; i1 = i1 < 0 ? -i1 : i1;
        int i3 = i + 1; i3 = i3 > TT - 1 ? 2 * (TT - 1) - i3 : i3;
        int i4 = i + 2; i4 = i4 > TT - 1 ? 2 * (TT - 1) - i4 : i4;
        v0 = buf[src][i0]; v1 = buf[src][i1]; v2 = buf[src][i];
        v3 = buf[src][i3]; v4 = buf[src][i4];
      }
      MSWAP(v0, v1); MSWAP(v3, v4); MSWAP(v2, v4); MSWAP(v2, v3);
      MSWAP(v1, v4); MSWAP(v0, v3); MSWAP(v0, v2); MSWAP(v1, v3);
      MSWAP(v1, v2);
      buf[1 - src][i] = v2;
    }
    __syncthreads();
    src = 1 - src;
  }
  for (int i = tid; i < TT; i += 256) mask[(size_t)b * TT + i] = buf[src][i];
}

extern "C" void kernel_launch(void* const* d_in, const int* in_sizes, int n_in,
                              void* d_out, int out_size, void* d_ws, size_t ws_size,
                              hipStream_t stream) {
  const float* x    = (const float*)d_in[0];
  const float* e    = (const float*)d_in[1];
  const float* u    = (const float*)d_in[2];
  const float* WihF = (const float*)d_in[3];
  const float* WhhF = (const float*)d_in[4];
  const float* bihF = (const float*)d_in[5];
  const float* bhhF = (const float*)d_in[6];
  const float* WihB = (const float*)d_in[7];
  const float* WhhB = (const float*)d_in[8];
  const float* bihB = (const float*)d_in[9];
  const float* bhhB = (const float*)d_in[10];
  const float* gamma= (const float*)d_in[11];
  const float* beta = (const float*)d_in[12];
  const float* Wlin = (const float*)d_in[13];
  const float* blin = (const float*)d_in[14];

  float* ws = (float*)d_ws;
  float4* wq    = (float4*)(ws + OFF_WQ);
  float* projF  = ws + OFF_PROJF;
  float* projB  = ws + OFF_PROJB;
  float* hbuf   = ws + OFF_HBUF;
  float* stats  = ws + OFF_STATS;
  float* hstate = ws + OFF_HSTATE;
  float* cstate = ws + OFF_CSTATE;
  float* hx     = ws + OFF_HX;
  int*   flags  = (int*)(ws + OFF_FLAGS);
  float* w2     = ws + OFF_W2;
  float* b2     = ws + OFF_B2;
  float* samp   = ws + OFF_SAMP;

  float* post = (float*)d_out;
  float* mask = (float*)d_out + (size_t)BB * TT * 2;

  hipLaunchKernelGGL(k0_init, dim3(512), dim3(256), 0, stream,
                     WhhF, WhhB, wq, stats, flags);
  for (int p = 0; p < NPH; ++p) {
    int t0f = p * CHUNK;
    int t0b = (NPH - 1 - p) * CHUNK;
    hipLaunchKernelGGL(k1_proj, dim3(4, 16, 32), dim3(256), 0, stream,
                       x, WihF, bihF, bhhF, WihB, bihB, bhhB, projF, projB, t0f, t0b);
    hipLaunchKernelGGL(k2_rec, dim3(256), dim3(512), 0, stream,
                       wq, projF, projB, hbuf, hx, flags,
                       hstate, cstate, stats, t0f, t0b, p == 0 ? 1 : 0, p * CHUNK);
  }
  hipLaunchKernelGGL(k3_prep, dim3(1), dim3(512), 0, stream,
                     stats, gamma, beta, Wlin, blin, w2, b2);
  hipLaunchKernelGGL(k4_post, dim3(8192), dim3(256), 0, stream,
                     hbuf, w2, b2, u, e, post, samp);
  hipLaunchKernelGGL(k5_median, dim3(16), dim3(256), 0, stream, samp, mask);
}